// Round 9
// baseline (280.054 us; speedup 1.0000x reference)
//
#include <hip/hip_runtime.h>
#include <cstdint>

// Problem constants (MultiHeadGraphAttentionLayer_86638080295672)
#define B_    8
#define N_    2048
#define FIN_  256
#define H_    4
#define D_    64
#define NEG_SLOPE 0.2f
#define LOG2E 1.44269504f

typedef __bf16    bf16x8 __attribute__((ext_vector_type(8)));
typedef _Float16  f16x8  __attribute__((ext_vector_type(8)));
typedef uint16_t  u16x8  __attribute__((ext_vector_type(8)));
typedef float     fx4    __attribute__((ext_vector_type(4)));

static __device__ __forceinline__ float bf2f(uint16_t u) {
    union { uint32_t u; float f; } c; c.u = ((uint32_t)u) << 16; return c.f;
}
static __device__ __forceinline__ uint16_t f2bf(float f) {
    union { float f; uint32_t u; } c; c.f = f;
    return (uint16_t)((c.u + 0x7fffu + ((c.u >> 16) & 1u)) >> 16);  // RNE
}
static __device__ __forceinline__ uint16_t f2h(float f) {
    const _Float16 h = (_Float16)f;                 // v_cvt_f16_f32 RNE
    return __builtin_bit_cast(uint16_t, h);
}
static __device__ __forceinline__ bf16x8 ldbf8(const uint16_t* p) {
    return *(const bf16x8*)p;
}
static __device__ __forceinline__ f16x8 ldf8(const uint16_t* p) {
    return *(const f16x8*)p;
}
// pack two fp32 into one dword of bf16 (truncation; bias cancels in O/l ratio)
static __device__ __forceinline__ uint32_t pkbf_trunc(float lo, float hi) {
    const uint32_t ul = __builtin_bit_cast(uint32_t, lo);
    const uint32_t uh = __builtin_bit_cast(uint32_t, hi);
    return (ul >> 16) | (uh & 0xFFFF0000u);
}
// convert 8 contiguous fp32 -> f16x8 (RNE)
static __device__ __forceinline__ f16x8 cvt8(const float* p) {
    const float4 x0 = *(const float4*)p;
    const float4 x1 = *(const float4*)(p + 4);
    const float f[8] = {x0.x, x0.y, x0.z, x0.w, x1.x, x1.y, x1.z, x1.w};
    f16x8 r;
    #pragma unroll
    for (int j = 0; j < 8; ++j) r[j] = (_Float16)f[j];
    return r;
}

// ---------------------------------------------------------------------------
// Kernel 0 (prep): Wt_f16[h][d][f] = (fp16) W[h][f][d]
// ---------------------------------------------------------------------------
__global__ void prep_kernel(const float* __restrict__ W,
                            uint16_t* __restrict__ Wt_f16) {
    const int h  = blockIdx.x >> 4;
    const int d4 = blockIdx.x & 15;
    const int f  = threadIdx.x;
    const float4 w = *(const float4*)(W + (((size_t)h * FIN_ + f) * D_ + d4 * 4));
    const float vv[4] = {w.x, w.y, w.z, w.w};
    #pragma unroll
    for (int j = 0; j < 4; ++j) {
        const int d = d4 * 4 + j;
        Wt_f16[((size_t)h * D_ + d) * FIN_ + f] = f2h(vv[j]);
    }
}

// ---------------------------------------------------------------------------
// Kernel 1: P = h @ W, single-product fp16 MFMA. Writes P_f16 [BH][N][D]
// (Q/K source) and Pt_bf16 [BH][D][N] (V source for the bf16 PV MFMA).
// ---------------------------------------------------------------------------
__global__ __launch_bounds__(256, 2) void proj_kernel(
    const float*    __restrict__ hin,
    const uint16_t* __restrict__ Wt_f16,
    uint16_t* __restrict__ P_f16,
    uint16_t* __restrict__ Pt_bf16)
{
    __shared__ __align__(16) uint16_t plds[4][16][72];

    const int lane = threadIdx.x & 63, wave = threadIdx.x >> 6;
    const int quad = lane >> 4, l15 = lane & 15;

    const int b  = blockIdx.y;
    const int h0 = blockIdx.z * 2;
    const int n0 = blockIdx.x * 64 + wave * 16;

    const float* arow = hin + ((size_t)b * N_ + n0 + l15) * FIN_ + quad * 8;

    fx4 acc[2][4];
    #pragma unroll
    for (int hh = 0; hh < 2; ++hh)
        #pragma unroll
        for (int t = 0; t < 4; ++t) acc[hh][t] = (fx4)(0.0f);

    #pragma unroll
    for (int k0 = 0; k0 < FIN_; k0 += 32) {
        const f16x8 a = cvt8(arow + k0);   // A[m=l15][k=quad*8+j]
        #pragma unroll
        for (int hh = 0; hh < 2; ++hh) {
            const uint16_t* wb = Wt_f16 + (size_t)(h0 + hh) * D_ * FIN_;
            #pragma unroll
            for (int t = 0; t < 4; ++t) {
                const f16x8 bb = ldf8(wb + (size_t)(t * 16 + l15) * FIN_ + k0 + quad * 8);
                acc[hh][t] = __builtin_amdgcn_mfma_f32_16x16x32_f16(a, bb, acc[hh][t], 0, 0, 0);
            }
        }
    }

    #pragma unroll
    for (int hh = 0; hh < 2; ++hh) {
        const int bh = b * H_ + h0 + hh;
        // pass 1: fp16 -> plds -> row-contiguous P_f16 (b128 stores)
        #pragma unroll
        for (int t = 0; t < 4; ++t)
            #pragma unroll
            for (int r = 0; r < 4; ++r)
                plds[wave][quad * 4 + r][t * 16 + l15] = f2h(acc[hh][t][r]);
        {
            const uint16_t* base = &plds[wave][l15][0];
            const int4 r0 = *(const int4*)(base + quad * 8);
            const int4 r1 = *(const int4*)(base + quad * 8 + 32);
            uint16_t* pg = P_f16 + ((size_t)bh * N_ + n0 + l15) * D_;
            *(int4*)(pg + quad * 8)      = r0;
            *(int4*)(pg + quad * 8 + 32) = r1;
        }
        // pass 2: bf16 -> plds -> transposed Pt_bf16 (b128 stores, lane = d)
        #pragma unroll
        for (int t = 0; t < 4; ++t)
            #pragma unroll
            for (int r = 0; r < 4; ++r)
                plds[wave][quad * 4 + r][t * 16 + l15] = f2bf(acc[hh][t][r]);
        {
            uint32_t u[8];
            #pragma unroll
            for (int j = 0; j < 8; ++j) {
                const uint16_t e0 = plds[wave][2 * j][lane];
                const uint16_t e1 = plds[wave][2 * j + 1][lane];
                u[j] = (uint32_t)e0 | ((uint32_t)e1 << 16);
            }
            uint16_t* pt = Pt_bf16 + ((size_t)bh * D_ + lane) * N_ + n0;
            int4 s0, s1;
            s0.x = u[0]; s0.y = u[1]; s0.z = u[2]; s0.w = u[3];
            s1.x = u[4]; s1.y = u[5]; s1.z = u[6]; s1.w = u[7];
            *(int4*)pt       = s0;
            *(int4*)(pt + 8) = s1;
        }
    }
}

// ---------------------------------------------------------------------------
// Kernel 2: flash attention, S^T formulation, diagonal-shift softmax (exact;
// overflow-safe). 4 waves x 32 Q-rows = 128 rows/block, 2 blocks/CU (the
// round-7 verified sweet spot; 64-row waves at 1/SIMD regressed — no TLP).
// K staged in LDS (double-buffered); V A-frags loaded DIRECTLY from global
// (Pt_bf16 rows), issued at loop-top and consumed at loop-bottom -> removes
// sV staging + 8 LDS reads/wave-iter from the bottleneck LDS pipe.
// ---------------------------------------------------------------------------
__global__ __launch_bounds__(256, 2) void attn_kernel(
    const uint16_t* __restrict__ P_f16,    // [BH][N][D] fp16 (Q,K)
    const uint16_t* __restrict__ Pt_bf16,  // [BH][D][N] bf16 (V)
    const float*    __restrict__ hin,
    float*          __restrict__ out)
{
    __shared__ __align__(16) uint16_t sK[2][64 * 64];
    __shared__ __align__(16) uint16_t plds[4][32][72];

    const int tid  = threadIdx.x;
    const int lane = tid & 63, wave = tid >> 6;
    const int quad = lane >> 4, l15 = lane & 15;

    const int bh = blockIdx.y, b = bh >> 2, hd = bh & 3;
    const int n0 = blockIdx.x * 128 + wave * 32;

    const uint16_t* Pf = P_f16   + (size_t)bh * N_ * D_;
    const uint16_t* Pt = Pt_bf16 + (size_t)bh * D_ * N_;

    // Q B-frags, 2 m-tiles, pre-scaled by log2e (exp -> exp2; lrelu commutes)
    f16x8 qf[2][2];
    #pragma unroll
    for (int mt = 0; mt < 2; ++mt) {
        const uint16_t* qrow = Pf + (size_t)(n0 + mt * 16 + l15) * D_ + quad * 8;
        qf[mt][0] = ldf8(qrow); qf[mt][1] = ldf8(qrow + 32);
        const _Float16 c = (_Float16)LOG2E;
        #pragma unroll
        for (int j = 0; j < 8; ++j) { qf[mt][0][j] *= c; qf[mt][1][j] *= c; }
    }

    // per-row shift C[mt] = s_diag * log2e = |qhat|^2 / log2e
    float C[2];
    #pragma unroll
    for (int mt = 0; mt < 2; ++mt) {
        float acc = 0.0f;
        #pragma unroll
        for (int j = 0; j < 8; ++j) {
            const float a0 = (float)qf[mt][0][j], a1 = (float)qf[mt][1][j];
            acc += a0 * a0 + a1 * a1;
        }
        acc += __shfl_xor(acc, 16);
        acc += __shfl_xor(acc, 32);
        C[mt] = acc * (1.0f / LOG2E);
    }

    // all-ones bf16 A-frag for the denominator MFMA
    bf16x8 ones;
    {
        u16x8 ov;
        #pragma unroll
        for (int j = 0; j < 8; ++j) ov[j] = 0x3F80;
        ones = __builtin_bit_cast(bf16x8, ov);
    }

    // K staging: thread covers slots tid, tid+256 of the 512-slot buffer.
    // LDS[row][c] = G[row][c ^ (row&7)] (swizzle folded into global address)
    const int i0 = tid, i1 = tid + 256;
    const int r0s = i0 >> 3, c0s = i0 & 7;
    const int r1s = i1 >> 3, c1s = i1 & 7;
    const uint16_t* gK0 = Pf + (size_t)r0s * D_ + (c0s ^ (r0s & 7)) * 8;
    const uint16_t* gK1 = Pf + (size_t)r1s * D_ + (c1s ^ (r1s & 7)) * 8;

    // V A-frag global base: A[m=d=dt*16+l15][k=key=quad*8+j (+32)]
    const uint16_t* vbase = Pt + (size_t)l15 * N_ + quad * 8;

    // prologue: K tile 0 -> buf 0; K tile 1 -> regs
    {
        int4 a = *(const int4*)gK0, bb = *(const int4*)gK1;
        ((int4*)sK[0])[i0] = a;  ((int4*)sK[0])[i1] = bb;
    }
    int4 rK0 = *(const int4*)(gK0 + (size_t)64 * D_);
    int4 rK1 = *(const int4*)(gK1 + (size_t)64 * D_);

    fx4 oacc[2][4], lacc[2];
    #pragma unroll
    for (int mt = 0; mt < 2; ++mt) {
        lacc[mt] = (fx4)(0.0f);
        #pragma unroll
        for (int dt = 0; dt < 4; ++dt) oacc[mt][dt] = (fx4)(0.0f);
    }

    const int cc = quad ^ (l15 & 7);   // swizzled chunk for K frag reads

    __syncthreads();
    for (int it = 0; it < N_ / 64; ++it) {
        const int cur = it & 1;
        const int key0 = it * 64;

        // ---- V frags for this tile: direct global loads (consumed at PV,
        // ~1000 cyc later -> latency hidden under QK + softmax)
        bf16x8 vg[4][2];
        #pragma unroll
        for (int dt = 0; dt < 4; ++dt) {
            const uint16_t* vr = vbase + (size_t)(dt * 16) * N_ + key0;
            vg[dt][0] = ldbf8(vr);
            vg[dt][1] = ldbf8(vr + 32);
        }

        // write K tile it+1 (in regs) into the other buffer
        if (it < N_ / 64 - 1) {
            ((int4*)sK[cur ^ 1])[i0] = rK0; ((int4*)sK[cur ^ 1])[i1] = rK1;
        }
        // prefetch K tile it+2 into regs
        if (it < N_ / 64 - 2) {
            const size_t ko = (size_t)(it + 2) * 64;
            rK0 = *(const int4*)(gK0 + ko * D_);
            rK1 = *(const int4*)(gK1 + ko * D_);
        }

        // ---- S^T = K Q^T : lane holds keys {t*16+quad*4+r} of its Q-rows
        fx4 s[2][4];
        #pragma unroll
        for (int mt = 0; mt < 2; ++mt)
            #pragma unroll
            for (int t = 0; t < 4; ++t) s[mt][t] = (fx4)(0.0f);
        #pragma unroll
        for (int t = 0; t < 4; ++t) {
            const uint16_t* kb = &sK[cur][(t * 16 + l15) * 64];
            const f16x8 k0 = ldf8(kb + cc * 8);
            const f16x8 k1 = ldf8(kb + (cc ^ 4) * 8);
            #pragma unroll
            for (int mt = 0; mt < 2; ++mt) {
                s[mt][t] = __builtin_amdgcn_mfma_f32_16x16x32_f16(k0, qf[mt][0], s[mt][t], 0, 0, 0);
                s[mt][t] = __builtin_amdgcn_mfma_f32_16x16x32_f16(k1, qf[mt][1], s[mt][t], 0, 0, 0);
            }
        }

        // ---- probs = exp2(lrelu(s)*log2e - C) ; pack bf16 -> plds
        #pragma unroll
        for (int mt = 0; mt < 2; ++mt) {
            #pragma unroll
            for (int t = 0; t < 4; ++t) {
                float e[4];
                #pragma unroll
                for (int r = 0; r < 4; ++r) {
                    const float v = s[mt][t][r];
                    e[r] = __builtin_amdgcn_exp2f(fmaxf(v, NEG_SLOPE * v) - C[mt]);
                }
                const uint32_t w0 = pkbf_trunc(e[0], e[1]);
                const uint32_t w1 = pkbf_trunc(e[2], e[3]);
                *(uint2*)&plds[wave][mt * 16 + l15][t * 16 + quad * 4] = make_uint2(w0, w1);
            }
        }

        // B-frags of probs: B[k=key=c*32+quad*8+j][n=qrow=l15]
        bf16x8 a[2][2];
        #pragma unroll
        for (int mt = 0; mt < 2; ++mt) {
            const uint16_t* pb = &plds[wave][mt * 16 + l15][0];
            a[mt][0] = ldbf8(pb + quad * 8);
            a[mt][1] = ldbf8(pb + quad * 8 + 32);
        }

        // ---- denominator: lacc[m][n=qrow] += sum_k probs  (matrix pipe)
        #pragma unroll
        for (int mt = 0; mt < 2; ++mt) {
            lacc[mt] = __builtin_amdgcn_mfma_f32_16x16x32_bf16(ones, a[mt][0], lacc[mt], 0, 0, 0);
            lacc[mt] = __builtin_amdgcn_mfma_f32_16x16x32_bf16(ones, a[mt][1], lacc[mt], 0, 0, 0);
        }
        // ---- O^T += V^T x P^T  (V frags from global, loaded at loop-top)
        #pragma unroll
        for (int dt = 0; dt < 4; ++dt) {
            #pragma unroll
            for (int mt = 0; mt < 2; ++mt) {
                oacc[mt][dt] = __builtin_amdgcn_mfma_f32_16x16x32_bf16(vg[dt][0], a[mt][0], oacc[mt][dt], 0, 0, 0);
                oacc[mt][dt] = __builtin_amdgcn_mfma_f32_16x16x32_bf16(vg[dt][1], a[mt][1], oacc[mt][dt], 0, 0, 0);
            }
        }
        __syncthreads();
    }

    // ---- epilogue: O^T layout row(d)=dt*16+quad*4+r, col(qrow)=l15.
    // lacc rows are all identical = l(qrow=l15): no cross-lane reduce needed.
    #pragma unroll
    for (int mt = 0; mt < 2; ++mt) {
        const float inv = 1.0f / lacc[mt][0];
        const size_t rowbase = ((size_t)b * N_ + n0 + mt * 16 + l15) * FIN_ + hd * D_;
        #pragma unroll
        for (int dt = 0; dt < 4; ++dt) {
            const size_t idx = rowbase + dt * 16 + quad * 4;
            const float4 hv = *(const float4*)&hin[idx];
            float4 o;
            o.x = oacc[mt][dt][0] * inv + hv.x;
            o.y = oacc[mt][dt][1] * inv + hv.y;
            o.z = oacc[mt][dt][2] * inv + hv.z;
            o.w = oacc[mt][dt][3] * inv + hv.w;
            *(float4*)&out[idx] = o;
        }
    }
}

// ---------------------------------------------------------------------------
extern "C" void kernel_launch(void* const* d_in, const int* in_sizes, int n_in,
                              void* d_out, int out_size, void* d_ws, size_t ws_size,
                              hipStream_t stream) {
    const float* hin = (const float*)d_in[0];   // h   [8,2048,256] fp32
    // d_in[1] = adj — dead input (never used by the reference math)
    const float* W   = (const float*)d_in[2];   // W   [4,256,64]   fp32
    float* out = (float*)d_out;

    // workspace (u16 elems): Wt_f16 | P_f16 | Pt_bf16  (~17 MB)
    uint16_t* Wt_f16  = (uint16_t*)d_ws;
    uint16_t* P_f16   = Wt_f16 + (size_t)H_ * D_ * FIN_;
    uint16_t* Pt_bf16 = P_f16  + (size_t)B_ * H_ * N_ * D_;

    hipLaunchKernelGGL(prep_kernel, dim3(H_ * 16),         dim3(FIN_), 0, stream, W, Wt_f16);
    hipLaunchKernelGGL(proj_kernel, dim3(N_/64, B_, H_/2), dim3(256),  0, stream,
                       hin, Wt_f16, P_f16, Pt_bf16);
    hipLaunchKernelGGL(attn_kernel, dim3(N_/128, B_*H_),   dim3(256),  0, stream,
                       P_f16, Pt_bf16, hin, out);
}

// Round 10
// 246.643 us; speedup vs baseline: 1.1355x; 1.1355x over previous
//
#include <hip/hip_runtime.h>
#include <cstdint>

// Problem constants (MultiHeadGraphAttentionLayer_86638080295672)
#define B_    8
#define N_    2048
#define FIN_  256
#define H_    4
#define D_    64
#define NEG_SLOPE 0.2f
#define LOG2E 1.44269504f

typedef __bf16    bf16x8 __attribute__((ext_vector_type(8)));
typedef _Float16  f16x8  __attribute__((ext_vector_type(8)));
typedef __fp16    fp16x2 __attribute__((ext_vector_type(2)));  // cvt_pkrtz return type
typedef uint16_t  u16x8  __attribute__((ext_vector_type(8)));
typedef float     fx4    __attribute__((ext_vector_type(4)));

static __device__ __forceinline__ uint16_t f2h(float f) {
    const _Float16 h = (_Float16)f;                 // v_cvt_f16_f32 RNE
    return __builtin_bit_cast(uint16_t, h);
}
static __device__ __forceinline__ f16x8 ldf8(const uint16_t* p) {
    return *(const f16x8*)p;
}
static __device__ __forceinline__ uint32_t pkh2(float a, float b) {
    const fp16x2 h = __builtin_amdgcn_cvt_pkrtz(a, b);  // v_cvt_pkrtz_f16_f32
    return __builtin_bit_cast(uint32_t, h);
}
// convert 8 contiguous fp32 -> f16x8 (RNE)
static __device__ __forceinline__ f16x8 cvt8(const float* p) {
    const float4 x0 = *(const float4*)p;
    const float4 x1 = *(const float4*)(p + 4);
    const float f[8] = {x0.x, x0.y, x0.z, x0.w, x1.x, x1.y, x1.z, x1.w};
    f16x8 r;
    #pragma unroll
    for (int j = 0; j < 8; ++j) r[j] = (_Float16)f[j];
    return r;
}

// ---------------------------------------------------------------------------
// Kernel 0 (prep): Wt_f16[h][d][f] = (fp16) W[h][f][d]
// ---------------------------------------------------------------------------
__global__ void prep_kernel(const float* __restrict__ W,
                            uint16_t* __restrict__ Wt_f16) {
    const int h  = blockIdx.x >> 4;
    const int d4 = blockIdx.x & 15;
    const int f  = threadIdx.x;
    const float4 w = *(const float4*)(W + (((size_t)h * FIN_ + f) * D_ + d4 * 4));
    const float vv[4] = {w.x, w.y, w.z, w.w};
    #pragma unroll
    for (int j = 0; j < 4; ++j) {
        const int d = d4 * 4 + j;
        Wt_f16[((size_t)h * D_ + d) * FIN_ + f] = f2h(vv[j]);
    }
}

// ---------------------------------------------------------------------------
// Kernel 1: P = h @ W, single-product fp16 MFMA. Writes P_f16 [BH][N][D]
// (Q/K source) and Pt_f16 [BH][D][N] (V source). One fp16 plds pass serves
// both the row-contiguous store and the transposed store.
// ---------------------------------------------------------------------------
__global__ __launch_bounds__(256, 2) void proj_kernel(
    const float*    __restrict__ hin,
    const uint16_t* __restrict__ Wt_f16,
    uint16_t* __restrict__ P_f16,
    uint16_t* __restrict__ Pt_f16)
{
    __shared__ __align__(16) uint16_t plds[4][16][72];

    const int lane = threadIdx.x & 63, wave = threadIdx.x >> 6;
    const int quad = lane >> 4, l15 = lane & 15;

    const int b  = blockIdx.y;
    const int h0 = blockIdx.z * 2;
    const int n0 = blockIdx.x * 64 + wave * 16;

    const float* arow = hin + ((size_t)b * N_ + n0 + l15) * FIN_ + quad * 8;

    fx4 acc[2][4];
    #pragma unroll
    for (int hh = 0; hh < 2; ++hh)
        #pragma unroll
        for (int t = 0; t < 4; ++t) acc[hh][t] = (fx4)(0.0f);

    #pragma unroll
    for (int k0 = 0; k0 < FIN_; k0 += 32) {
        const f16x8 a = cvt8(arow + k0);   // A[m=l15][k=quad*8+j]
        #pragma unroll
        for (int hh = 0; hh < 2; ++hh) {
            const uint16_t* wb = Wt_f16 + (size_t)(h0 + hh) * D_ * FIN_;
            #pragma unroll
            for (int t = 0; t < 4; ++t) {
                const f16x8 bb = ldf8(wb + (size_t)(t * 16 + l15) * FIN_ + k0 + quad * 8);
                acc[hh][t] = __builtin_amdgcn_mfma_f32_16x16x32_f16(a, bb, acc[hh][t], 0, 0, 0);
            }
        }
    }

    #pragma unroll
    for (int hh = 0; hh < 2; ++hh) {
        const int bh = b * H_ + h0 + hh;
        // C-layout -> plds as fp16 (wave-private, lockstep)
        #pragma unroll
        for (int t = 0; t < 4; ++t)
            #pragma unroll
            for (int r = 0; r < 4; ++r)
                plds[wave][quad * 4 + r][t * 16 + l15] = f2h(acc[hh][t][r]);

        // rows -> P_f16 (b128 stores)
        {
            const uint16_t* base = &plds[wave][l15][0];
            const int4 r0 = *(const int4*)(base + quad * 8);
            const int4 r1 = *(const int4*)(base + quad * 8 + 32);
            uint16_t* pg = P_f16 + ((size_t)bh * N_ + n0 + l15) * D_;
            *(int4*)(pg + quad * 8)      = r0;
            *(int4*)(pg + quad * 8 + 32) = r1;
        }
        // cols -> Pt_f16 (transpose; 2 b128 stores per lane, lane = d)
        {
            uint32_t u[8];
            #pragma unroll
            for (int j = 0; j < 8; ++j) {
                const uint16_t e0 = plds[wave][2 * j][lane];
                const uint16_t e1 = plds[wave][2 * j + 1][lane];
                u[j] = (uint32_t)e0 | ((uint32_t)e1 << 16);
            }
            uint16_t* pt = Pt_f16 + ((size_t)bh * D_ + lane) * N_ + n0;
            int4 s0, s1;
            s0.x = u[0]; s0.y = u[1]; s0.z = u[2]; s0.w = u[3];
            s1.x = u[4]; s1.y = u[5]; s1.z = u[6]; s1.w = u[7];
            *(int4*)pt       = s0;
            *(int4*)(pt + 8) = s1;
        }
    }
}

// ---------------------------------------------------------------------------
// Kernel 2: flash attention, S^T formulation, diagonal-shift softmax (exact;
// shift folded into the MFMA accumulator init: s' = score*log2e - C, probs =
// exp2(max(s', 0.2*s' - 0.8C))). 4 waves x 32 Q-rows, 2 blocks/CU (verified
// sweet spot); K AND V staged in LDS, double-buffered, 1 barrier/iter.
// fp16 probs via v_cvt_pkrtz; denominator via ones-MFMA on the matrix pipe.
// ---------------------------------------------------------------------------
__global__ __launch_bounds__(256, 2) void attn_kernel(
    const uint16_t* __restrict__ P_f16,   // [BH][N][D] fp16 (Q,K)
    const uint16_t* __restrict__ Pt_f16,  // [BH][D][N] fp16 (V)
    const float*    __restrict__ hin,
    float*          __restrict__ out)
{
    __shared__ __align__(16) uint16_t sK[2][64 * 64];
    __shared__ __align__(16) uint16_t sV[2][64 * 64];
    __shared__ __align__(16) uint16_t plds[4][32][72];

    const int tid  = threadIdx.x;
    const int lane = tid & 63, wave = tid >> 6;
    const int quad = lane >> 4, l15 = lane & 15;

    const int bh = blockIdx.y, b = bh >> 2, hd = bh & 3;
    const int n0 = blockIdx.x * 128 + wave * 32;

    const uint16_t* Pf = P_f16  + (size_t)bh * N_ * D_;
    const uint16_t* Pt = Pt_f16 + (size_t)bh * D_ * N_;

    // Q B-frags, 2 m-tiles, pre-scaled by log2e (exp -> exp2; lrelu commutes)
    f16x8 qf[2][2];
    #pragma unroll
    for (int mt = 0; mt < 2; ++mt) {
        const uint16_t* qrow = Pf + (size_t)(n0 + mt * 16 + l15) * D_ + quad * 8;
        qf[mt][0] = ldf8(qrow); qf[mt][1] = ldf8(qrow + 32);
        const _Float16 c = (_Float16)LOG2E;
        #pragma unroll
        for (int j = 0; j < 8; ++j) { qf[mt][0][j] *= c; qf[mt][1][j] *= c; }
    }

    // per-row shift C[mt] = s_diag * log2e = |qhat|^2 / log2e ; c2 = -0.8*C
    float C[2], c2[2];
    #pragma unroll
    for (int mt = 0; mt < 2; ++mt) {
        float acc = 0.0f;
        #pragma unroll
        for (int j = 0; j < 8; ++j) {
            const float a0 = (float)qf[mt][0][j], a1 = (float)qf[mt][1][j];
            acc += a0 * a0 + a1 * a1;
        }
        acc += __shfl_xor(acc, 16);
        acc += __shfl_xor(acc, 32);
        C[mt]  = acc * (1.0f / LOG2E);
        c2[mt] = -0.8f * C[mt];
    }

    // all-ones fp16 A-frag for the denominator MFMA
    f16x8 ones;
    {
        u16x8 ov;
        #pragma unroll
        for (int j = 0; j < 8; ++j) ov[j] = 0x3C00;   // fp16 1.0
        ones = __builtin_bit_cast(f16x8, ov);
    }

    // staging: thread covers slots tid, tid+256 of each 512-slot buffer.
    // LDS[row][c] = G[row][c ^ (row&7)] (swizzle folded into global address)
    const int i0 = tid, i1 = tid + 256;
    const int r0s = i0 >> 3, c0s = i0 & 7;
    const int r1s = i1 >> 3, c1s = i1 & 7;
    const uint16_t* gK0 = Pf + (size_t)r0s * D_ + (c0s ^ (r0s & 7)) * 8;
    const uint16_t* gK1 = Pf + (size_t)r1s * D_ + (c1s ^ (r1s & 7)) * 8;
    const uint16_t* gV0 = Pt + (size_t)r0s * N_ + (c0s ^ (r0s & 7)) * 8;
    const uint16_t* gV1 = Pt + (size_t)r1s * N_ + (c1s ^ (r1s & 7)) * 8;

    // prologue: tile 0 -> buf 0; tile 1 -> regs
    {
        int4 a = *(const int4*)gK0, bb = *(const int4*)gK1;
        int4 c = *(const int4*)gV0, d  = *(const int4*)gV1;
        ((int4*)sK[0])[i0] = a;  ((int4*)sK[0])[i1] = bb;
        ((int4*)sV[0])[i0] = c;  ((int4*)sV[0])[i1] = d;
    }
    int4 rK0 = *(const int4*)(gK0 + (size_t)64 * D_);
    int4 rK1 = *(const int4*)(gK1 + (size_t)64 * D_);
    int4 rV0 = *(const int4*)(gV0 + 64);
    int4 rV1 = *(const int4*)(gV1 + 64);

    fx4 oacc[2][4], lacc[2];
    #pragma unroll
    for (int mt = 0; mt < 2; ++mt) {
        lacc[mt] = (fx4)(0.0f);
        #pragma unroll
        for (int dt = 0; dt < 4; ++dt) oacc[mt][dt] = (fx4)(0.0f);
    }

    const int cc = quad ^ (l15 & 7);   // swizzled chunk for frag reads

    __syncthreads();
    for (int it = 0; it < N_ / 64; ++it) {
        const int cur = it & 1;
        // write tile it+1 (in regs) into the other buffer
        if (it < N_ / 64 - 1) {
            ((int4*)sK[cur ^ 1])[i0] = rK0; ((int4*)sK[cur ^ 1])[i1] = rK1;
            ((int4*)sV[cur ^ 1])[i0] = rV0; ((int4*)sV[cur ^ 1])[i1] = rV1;
        }
        // prefetch tile it+2 into regs
        if (it < N_ / 64 - 2) {
            const size_t ko = (size_t)(it + 2) * 64;
            rK0 = *(const int4*)(gK0 + ko * D_);
            rK1 = *(const int4*)(gK1 + ko * D_);
            rV0 = *(const int4*)(gV0 + ko);
            rV1 = *(const int4*)(gV1 + ko);
        }

        // ---- S^T - C = K Q^T - C : acc init at -C folds the softmax shift
        fx4 s[2][4];
        #pragma unroll
        for (int mt = 0; mt < 2; ++mt)
            #pragma unroll
            for (int t = 0; t < 4; ++t) s[mt][t] = (fx4)(-C[mt]);
        #pragma unroll
        for (int t = 0; t < 4; ++t) {
            const uint16_t* kb = &sK[cur][(t * 16 + l15) * 64];
            const f16x8 k0 = ldf8(kb + cc * 8);
            const f16x8 k1 = ldf8(kb + (cc ^ 4) * 8);
            #pragma unroll
            for (int mt = 0; mt < 2; ++mt) {
                s[mt][t] = __builtin_amdgcn_mfma_f32_16x16x32_f16(k0, qf[mt][0], s[mt][t], 0, 0, 0);
                s[mt][t] = __builtin_amdgcn_mfma_f32_16x16x32_f16(k1, qf[mt][1], s[mt][t], 0, 0, 0);
            }
        }

        // ---- probs = exp2(max(s', 0.2*s' - 0.8C)) ; pack fp16 -> plds
        #pragma unroll
        for (int mt = 0; mt < 2; ++mt) {
            #pragma unroll
            for (int t = 0; t < 4; ++t) {
                float e[4];
                #pragma unroll
                for (int r = 0; r < 4; ++r) {
                    const float v = s[mt][t][r];
                    e[r] = __builtin_amdgcn_exp2f(fmaxf(v, fmaf(NEG_SLOPE, v, c2[mt])));
                }
                const uint32_t w0 = pkh2(e[0], e[1]);
                const uint32_t w1 = pkh2(e[2], e[3]);
                *(uint2*)&plds[wave][mt * 16 + l15][t * 16 + quad * 4] = make_uint2(w0, w1);
            }
        }

        // B-frags of probs: B[k=key=c*32+quad*8+j][n=qrow=l15]
        f16x8 a[2][2];
        #pragma unroll
        for (int mt = 0; mt < 2; ++mt) {
            const uint16_t* pb = &plds[wave][mt * 16 + l15][0];
            a[mt][0] = ldf8(pb + quad * 8);
            a[mt][1] = ldf8(pb + quad * 8 + 32);
        }

        // ---- denominator: lacc[m][n=qrow] += sum_k probs  (matrix pipe)
        #pragma unroll
        for (int mt = 0; mt < 2; ++mt) {
            lacc[mt] = __builtin_amdgcn_mfma_f32_16x16x32_f16(ones, a[mt][0], lacc[mt], 0, 0, 0);
            lacc[mt] = __builtin_amdgcn_mfma_f32_16x16x32_f16(ones, a[mt][1], lacc[mt], 0, 0, 0);
        }
        // ---- O^T += V^T x P^T  (V frags from staged LDS)
        #pragma unroll
        for (int dt = 0; dt < 4; ++dt) {
            const uint16_t* vb = &sV[cur][(dt * 16 + l15) * 64];
            const f16x8 v0 = ldf8(vb + cc * 8);
            const f16x8 v1 = ldf8(vb + (cc ^ 4) * 8);
            #pragma unroll
            for (int mt = 0; mt < 2; ++mt) {
                oacc[mt][dt] = __builtin_amdgcn_mfma_f32_16x16x32_f16(v0, a[mt][0], oacc[mt][dt], 0, 0, 0);
                oacc[mt][dt] = __builtin_amdgcn_mfma_f32_16x16x32_f16(v1, a[mt][1], oacc[mt][dt], 0, 0, 0);
            }
        }
        __syncthreads();
    }

    // ---- epilogue: O^T layout row(d)=dt*16+quad*4+r, col(qrow)=l15.
    // lacc rows are all identical = l(qrow=l15): no cross-lane reduce needed.
    #pragma unroll
    for (int mt = 0; mt < 2; ++mt) {
        const float inv = 1.0f / lacc[mt][0];
        const size_t rowbase = ((size_t)b * N_ + n0 + mt * 16 + l15) * FIN_ + hd * D_;
        #pragma unroll
        for (int dt = 0; dt < 4; ++dt) {
            const size_t idx = rowbase + dt * 16 + quad * 4;
            const float4 hv = *(const float4*)&hin[idx];
            float4 o;
            o.x = oacc[mt][dt][0] * inv + hv.x;
            o.y = oacc[mt][dt][1] * inv + hv.y;
            o.z = oacc[mt][dt][2] * inv + hv.z;
            o.w = oacc[mt][dt][3] * inv + hv.w;
            *(float4*)&out[idx] = o;
        }
    }
}

// ---------------------------------------------------------------------------
extern "C" void kernel_launch(void* const* d_in, const int* in_sizes, int n_in,
                              void* d_out, int out_size, void* d_ws, size_t ws_size,
                              hipStream_t stream) {
    const float* hin = (const float*)d_in[0];   // h   [8,2048,256] fp32
    // d_in[1] = adj — dead input (never used by the reference math)
    const float* W   = (const float*)d_in[2];   // W   [4,256,64]   fp32
    float* out = (float*)d_out;

    // workspace (u16 elems): Wt_f16 | P_f16 | Pt_f16  (~17 MB)
    uint16_t* Wt_f16 = (uint16_t*)d_ws;
    uint16_t* P_f16  = Wt_f16 + (size_t)H_ * D_ * FIN_;
    uint16_t* Pt_f16 = P_f16  + (size_t)B_ * H_ * N_ * D_;

    hipLaunchKernelGGL(prep_kernel, dim3(H_ * 16),         dim3(FIN_), 0, stream, W, Wt_f16);
    hipLaunchKernelGGL(proj_kernel, dim3(N_/64, B_, H_/2), dim3(256),  0, stream,
                       hin, Wt_f16, P_f16, Pt_f16);
    hipLaunchKernelGGL(attn_kernel, dim3(N_/128, B_*H_),   dim3(256),  0, stream,
                       P_f16, Pt_f16, hin, out);
}